// Round 4
// baseline (2715.819 us; speedup 1.0000x reference)
//
#include <hip/hip_runtime.h>

// LSTMencoder: 2-layer biLSTM, B=256, T=2048, H=32 (4H=128 gates), in=32/64.
//
// Path A: time-chunked xg precompute (gemm, R2 LDS-staged version restored)
//   + dual-chain serial recurrence:
//   R3 findings: s_load gemm regressed 2x (scalar-load serialization) ->
//   reverted to R2 LDS gemm. rec is latency-bound at 0.5 waves/SIMD ->
//   one wave now runs BOTH directions of a batch element (independent
//   chains fill each other's stalls), h-broadcast via 512B double-buffered
//   LDS (9 DS ops vs 32 readlanes), float2 packed FMA (v_pk_fma_f32).
// Path B fallback: harness-verified fused kernel (tiny ws).

#define T_LEN 2048
#define BATCH 256
#define HID   32
#define PF    8

typedef __attribute__((ext_vector_type(2))) float f2;

__device__ __forceinline__ float frcp(float x) { return __builtin_amdgcn_rcpf(x); }
__device__ __forceinline__ float rdlane(float v, int k) {
    return __int_as_float(__builtin_amdgcn_readlane(__float_as_int(v), k));
}

template<int N>
__device__ __forceinline__ void load_row(float* dst, const float* __restrict__ src) {
#pragma unroll
    for (int i = 0; i < N / 4; ++i) {
        float4 v = reinterpret_cast<const float4*>(src)[i];
        dst[4*i+0] = v.x; dst[4*i+1] = v.y; dst[4*i+2] = v.z; dst[4*i+3] = v.w;
    }
}

__device__ __forceinline__ void load_row_f2_32(f2* dst, const float* __restrict__ src) {
#pragma unroll
    for (int i = 0; i < 8; ++i) {
        float4 v = reinterpret_cast<const float4*>(src)[i];
        f2 a; a.x = v.x; a.y = v.y;
        f2 b; b.x = v.z; b.y = v.w;
        dst[2*i]   = a;
        dst[2*i+1] = b;
    }
}

// ===================== Path A: chunked xg precompute GEMM (R2 version) ========
template<int LAYER>
__global__ __launch_bounds__(256) void xg_gemm_chunk(
        const float* __restrict__ OS, const float* __restrict__ IS,
        const float* __restrict__ h1,
        const float* __restrict__ Wih, const float* __restrict__ bih,
        const float* __restrict__ bhh, float* __restrict__ xg,
        int t_base, int C)
{
    constexpr int F  = (LAYER == 0) ? 32 : 64;
    constexpr int TT = 16;                      // timesteps per block (per dir)
    __shared__ float xs[2][TT][F];
    const int tid = threadIdx.x;
    const int d   = tid >> 7;                   // 0..1
    const int g   = tid & 127;                  // 0..127
    const int lt0 = blockIdx.x * TT;            // local chunk offset
    const int b   = blockIdx.y;

    // stage x tiles for BOTH dirs into LDS (coalesced in f)
    constexpr int TOT = 2 * TT * F;             // 1024 (L0) / 2048 (L1)
#pragma unroll
    for (int rep = 0; rep < TOT / 256; ++rep) {
        int flat = rep * 256 + tid;
        int d2  = flat / (TT * F);
        int rem = flat % (TT * F);
        int tt  = rem / F, f = rem % F;
        int tl  = t_base + lt0 + tt;
        int te  = d2 ? (T_LEN - 1 - tl) : tl;
        float v;
        if (LAYER == 0) {
            v = (f < 16) ? OS[((size_t)b * T_LEN + te) * 16 + f]
                         : IS[((size_t)b * T_LEN + (T_LEN - 1 - te)) * 16 + (f - 16)];
        } else {
            v = h1[((size_t)te * BATCH + b) * 64 + f];
        }
        xs[d2][tt][f] = v;
    }

    float w[F];
    load_row<F>(w, Wih + ((size_t)d * 128 + g) * F);
    const float bias = bih[d * 128 + g] + bhh[d * 128 + g];
    __syncthreads();

#pragma unroll
    for (int tt = 0; tt < TT; ++tt) {
        float a0 = bias, a1 = 0.f, a2 = 0.f, a3 = 0.f;
#pragma unroll
        for (int j = 0; j < F / 4; ++j) {
            float4 x = reinterpret_cast<const float4*>(xs[d][tt])[j];
            a0 = fmaf(x.x, w[4*j+0], a0);
            a1 = fmaf(x.y, w[4*j+1], a1);
            a2 = fmaf(x.z, w[4*j+2], a2);
            a3 = fmaf(x.w, w[4*j+3], a3);
        }
        xg[(((size_t)d * C + (lt0 + tt)) * BATCH + b) * 128 + g] = (a0 + a1) + (a2 + a3);
    }
}

// ===================== Path A: dual-chain serial recurrence =====================
// One wave per batch element b, running BOTH directions as independent chains.
// Lane l owns gates (l, 64+l) of each chain. h broadcast via parity-double-
// buffered LDS (single-wave block: DS in-order, no barrier). Packed f32 FMA.
template<int LAYER>
__global__ __launch_bounds__(64, 1) void lstm_rec2(
        const float* __restrict__ xg, const float* __restrict__ Whh,
        float* __restrict__ outp, float* __restrict__ state,
        int t_base, int C)
{
    const int l   = threadIdx.x;     // 0..63
    const int b   = blockIdx.x;      // 0..255
    const bool lo = (l < HID);
    const int xl  = (l + 32) & 63;   // swap partner

    // lane-constant nonlinearity params
    const float mB = lo ? -2.f : -1.f;
    const float kM = lo ?  2.f :  1.f;
    const float kA = lo ? -1.f :  0.f;

    // weights, packed f2: chain 0 = dir 0, chain 1 = dir 1
    f2 wA0[16], wB0[16], wA1[16], wB1[16];
    load_row_f2_32(wA0, Whh + ((size_t)0 * 128 + l) * HID);
    load_row_f2_32(wB0, Whh + ((size_t)0 * 128 + 64 + l) * HID);
    load_row_f2_32(wA1, Whh + ((size_t)1 * 128 + l) * HID);
    load_row_f2_32(wB1, Whh + ((size_t)1 * 128 + 64 + l) * HID);

    // restore state
    float c0 = 0.f, h0j = 0.f, c1 = 0.f, h1j = 0.f;
    if (t_base > 0 && lo) {
        c0  = state[(size_t)(0 * BATCH + b) * 64 + l];
        h0j = state[(size_t)(0 * BATCH + b) * 64 + 32 + l];
        c1  = state[(size_t)(1 * BATCH + b) * 64 + l];
        h1j = state[(size_t)(1 * BATCH + b) * 64 + 32 + l];
    }

    __shared__ __align__(16) float hbuf[2][2][HID];  // [parity][chain][j]
    if (lo) { hbuf[0][0][l] = h0j; hbuf[0][1][l] = h1j; }

    const size_t STRIDE = (size_t)BATCH * 128;
    const float* xp0 = xg + (size_t)b * 128;
    const float* xp1 = xg + (size_t)C * STRIDE + (size_t)b * 128;
    const float* pf0 = xp0 + (size_t)PF * STRIDE;
    const float* pf1 = xp1 + (size_t)PF * STRIDE;

    float ra0[PF], rb0[PF], ra1[PF], rb1[PF];
#pragma unroll
    for (int u = 0; u < PF; ++u) {
        ra0[u] = xp0[(size_t)u * STRIDE + l];
        rb0[u] = xp0[(size_t)u * STRIDE + 64 + l];
        ra1[u] = xp1[(size_t)u * STRIDE + l];
        rb1[u] = xp1[(size_t)u * STRIDE + 64 + l];
    }

    // incremental output pointers per chain
    float *op0, *op1;
    ptrdiff_t os0, os1;
    {
        const int teF = t_base;                 // dir 0
        const int teB = T_LEN - 1 - t_base;     // dir 1
        if constexpr (LAYER == 0) {
            op0 = outp + ((size_t)teF * BATCH + b) * 64 + 0 * HID + l;
            op1 = outp + ((size_t)teB * BATCH + b) * 64 + 1 * HID + l;
            os0 =  (ptrdiff_t)(BATCH * 64);
            os1 = -(ptrdiff_t)(BATCH * 64);
        } else {
            op0 = outp + ((size_t)b * T_LEN + teF) * 64 + 0 * HID + l;
            op1 = outp + ((size_t)b * T_LEN + teB) * 64 + 1 * HID + l;
            os0 =  (ptrdiff_t)64;
            os1 = -(ptrdiff_t)64;
        }
    }

#pragma unroll 1
    for (int tb = 0; tb < C; tb += PF) {
        // pin weights in VGPRs (prevent per-step rematerialized loads)
#pragma unroll
        for (int k = 0; k < 16; k += 4) {
            asm volatile("" : "+v"(wA0[k]), "+v"(wA0[k+1]), "+v"(wA0[k+2]), "+v"(wA0[k+3]));
            asm volatile("" : "+v"(wB0[k]), "+v"(wB0[k+1]), "+v"(wB0[k+2]), "+v"(wB0[k+3]));
            asm volatile("" : "+v"(wA1[k]), "+v"(wA1[k+1]), "+v"(wA1[k+2]), "+v"(wA1[k+3]));
            asm volatile("" : "+v"(wB1[k]), "+v"(wB1[k+1]), "+v"(wB1[k+2]), "+v"(wB1[k+3]));
        }

#pragma unroll
        for (int u = 0; u < PF; ++u) {
            const int p = u & 1;                // read parity (PF even => consistent)
            const float xa0 = ra0[u], xb0 = rb0[u];
            const float xa1 = ra1[u], xb1 = rb1[u];
            ra0[u] = pf0[l]; rb0[u] = pf0[64 + l]; pf0 += STRIDE;
            ra1[u] = pf1[l]; rb1[u] = pf1[64 + l]; pf1 += STRIDE;

            // ---- chain 0 (forward) ----
            {
                f2 h2[16];
                const float4* hb = reinterpret_cast<const float4*>(&hbuf[p][0][0]);
#pragma unroll
                for (int r = 0; r < 8; ++r) {
                    float4 q = hb[r];
                    f2 a; a.x = q.x; a.y = q.y;
                    f2 bb; bb.x = q.z; bb.y = q.w;
                    h2[2*r] = a; h2[2*r+1] = bb;
                }
                f2 aA[4], aB[4];
#pragma unroll
                for (int j = 0; j < 4; ++j) { aA[j] = (f2)(0.f); aB[j] = (f2)(0.f); }
#pragma unroll
                for (int k = 0; k < 16; ++k) {
                    aA[k & 3] = __builtin_elementwise_fma(h2[k], wA0[k], aA[k & 3]);
                    aB[k & 3] = __builtin_elementwise_fma(h2[k], wB0[k], aB[k & 3]);
                }
                f2 sA2 = (aA[0] + aA[1]) + (aA[2] + aA[3]);
                f2 sB2 = (aB[0] + aB[1]) + (aB[2] + aB[3]);
                const float accA = xa0 + sA2.x + sA2.y;
                const float accB = xb0 + sB2.x + sB2.y;

                const float sA = frcp(1.f + __expf(-accA));
                const float rB = frcp(1.f + __expf(mB * accB));
                const float sB = fmaf(kM, rB, kA);
                const float sf = __shfl(sA, xl);
                const float so = __shfl(sB, xl);
                c0 = fmaf(sf, c0, sA * sB);
                const float tc = fmaf(2.f, frcp(1.f + __expf(-2.f * c0)), -1.f);
                h0j = so * tc;
                if (lo) { *op0 = h0j; hbuf[p ^ 1][0][l] = h0j; }
                op0 += os0;
            }

            // ---- chain 1 (backward) ----
            {
                f2 h2[16];
                const float4* hb = reinterpret_cast<const float4*>(&hbuf[p][1][0]);
#pragma unroll
                for (int r = 0; r < 8; ++r) {
                    float4 q = hb[r];
                    f2 a; a.x = q.x; a.y = q.y;
                    f2 bb; bb.x = q.z; bb.y = q.w;
                    h2[2*r] = a; h2[2*r+1] = bb;
                }
                f2 aA[4], aB[4];
#pragma unroll
                for (int j = 0; j < 4; ++j) { aA[j] = (f2)(0.f); aB[j] = (f2)(0.f); }
#pragma unroll
                for (int k = 0; k < 16; ++k) {
                    aA[k & 3] = __builtin_elementwise_fma(h2[k], wA1[k], aA[k & 3]);
                    aB[k & 3] = __builtin_elementwise_fma(h2[k], wB1[k], aB[k & 3]);
                }
                f2 sA2 = (aA[0] + aA[1]) + (aA[2] + aA[3]);
                f2 sB2 = (aB[0] + aB[1]) + (aB[2] + aB[3]);
                const float accA = xa1 + sA2.x + sA2.y;
                const float accB = xb1 + sB2.x + sB2.y;

                const float sA = frcp(1.f + __expf(-accA));
                const float rB = frcp(1.f + __expf(mB * accB));
                const float sB = fmaf(kM, rB, kA);
                const float sf = __shfl(sA, xl);
                const float so = __shfl(sB, xl);
                c1 = fmaf(sf, c1, sA * sB);
                const float tc = fmaf(2.f, frcp(1.f + __expf(-2.f * c1)), -1.f);
                h1j = so * tc;
                if (lo) { *op1 = h1j; hbuf[p ^ 1][1][l] = h1j; }
                op1 += os1;
            }
        }
    }

    if (lo) {
        state[(size_t)(0 * BATCH + b) * 64 + l]      = c0;
        state[(size_t)(0 * BATCH + b) * 64 + 32 + l] = h0j;
        state[(size_t)(1 * BATCH + b) * 64 + l]      = c1;
        state[(size_t)(1 * BATCH + b) * 64 + 32 + l] = h1j;
    }
}

// ===================== Path B: previous verified fused kernel =====================
template<int LAYER>
__global__ __launch_bounds__(64, 1) void lstm_rec(
        const float* __restrict__ OS, const float* __restrict__ IS,
        const float* __restrict__ Wih, const float* __restrict__ Whh,
        const float* __restrict__ bih, const float* __restrict__ bhh,
        const float* __restrict__ h1in, float* __restrict__ outp)
{
    constexpr int F = (LAYER == 0) ? 32 : 64;
    const int l   = threadIdx.x;
    const int b   = blockIdx.x;
    const int dir = blockIdx.y;
    const int gA  = l;
    const int gB  = 64 + l;

    float wih_a[F], wih_b[F], whh_a[HID], whh_b[HID];
    load_row<F>(wih_a, Wih + ((size_t)dir * 128 + gA) * F);
    load_row<F>(wih_b, Wih + ((size_t)dir * 128 + gB) * F);
    load_row<HID>(whh_a, Whh + ((size_t)dir * 128 + gA) * HID);
    load_row<HID>(whh_b, Whh + ((size_t)dir * 128 + gB) * HID);
    const float biasA = bih[dir * 128 + gA] + bhh[dir * 128 + gA];
    const float biasB = bih[dir * 128 + gB] + bhh[dir * 128 + gB];

    float h[HID];
#pragma unroll
    for (int k = 0; k < HID; ++k) h[k] = 0.f;
    float c = 0.f;
    const bool lo = (l < HID);

    float4 X0[F / 4], X1[F / 4];

    auto load_x = [&](float4* X, int tl) {
        const int te = dir ? (T_LEN - 1 - tl) : tl;
        if constexpr (LAYER == 0) {
            const float4* p0 = reinterpret_cast<const float4*>(OS + ((size_t)b * T_LEN + te) * 16);
            const float4* p1 = reinterpret_cast<const float4*>(IS + ((size_t)b * T_LEN + (T_LEN - 1 - te)) * 16);
#pragma unroll
            for (int i = 0; i < 4; ++i) X[i] = p0[i];
#pragma unroll
            for (int i = 0; i < 4; ++i) X[4 + i] = p1[i];
        } else {
            const float4* p = reinterpret_cast<const float4*>(h1in + ((size_t)te * BATCH + b) * 64);
#pragma unroll
            for (int i = 0; i < F / 4; ++i) X[i] = p[i];
        }
    };

    auto step = [&](int tl, const float4* X) {
        const int te = dir ? (T_LEN - 1 - tl) : tl;
        float accA = biasA, accB = biasB;
#pragma unroll
        for (int i = 0; i < F / 4; ++i) {
            accA = fmaf(X[i].x, wih_a[4*i+0], accA);
            accA = fmaf(X[i].y, wih_a[4*i+1], accA);
            accA = fmaf(X[i].z, wih_a[4*i+2], accA);
            accA = fmaf(X[i].w, wih_a[4*i+3], accA);
            accB = fmaf(X[i].x, wih_b[4*i+0], accB);
            accB = fmaf(X[i].y, wih_b[4*i+1], accB);
            accB = fmaf(X[i].z, wih_b[4*i+2], accB);
            accB = fmaf(X[i].w, wih_b[4*i+3], accB);
        }
#pragma unroll
        for (int k = 0; k < HID; ++k) {
            accA = fmaf(h[k], whh_a[k], accA);
            accB = fmaf(h[k], whh_b[k], accB);
        }
        float sA = frcp(1.f + __expf(-accA));
        float argB = lo ? (-2.f * accB) : (-accB);
        float rB = frcp(1.f + __expf(argB));
        float sB = lo ? fmaf(2.f, rB, -1.f) : rB;
        float sf = __shfl(sA, (l + 32) & 63);
        float so = __shfl(sB, (l + 32) & 63);
        c = fmaf(sf, c, sA * sB);
        float tc = fmaf(2.f, frcp(1.f + __expf(-2.f * c)), -1.f);
        float hj = so * tc;
        if (lo) {
            if constexpr (LAYER == 0)
                outp[((size_t)te * BATCH + b) * 64 + dir * HID + l] = hj;
            else
                outp[((size_t)b * T_LEN + te) * 64 + dir * HID + l] = hj;
        }
#pragma unroll
        for (int k = 0; k < HID; ++k) h[k] = rdlane(hj, k);
    };

    load_x(X0, 0);
#pragma unroll 1
    for (int tt = 0; tt < T_LEN; tt += 2) {
        load_x(X1, tt + 1);
        step(tt, X0);
        int nx = tt + 2; if (nx > T_LEN - 1) nx = T_LEN - 1;
        load_x(X0, nx);
        step(tt + 1, X1);
    }
}

extern "C" void kernel_launch(void* const* d_in, const int* in_sizes, int n_in,
                              void* d_out, int out_size, void* d_ws, size_t ws_size,
                              hipStream_t stream) {
    const float* OS    = (const float*)d_in[0];
    const float* IS    = (const float*)d_in[1];
    const float* W_ih0 = (const float*)d_in[2];
    const float* W_hh0 = (const float*)d_in[3];
    const float* b_ih0 = (const float*)d_in[4];
    const float* b_hh0 = (const float*)d_in[5];
    const float* W_ih1 = (const float*)d_in[6];
    const float* W_hh1 = (const float*)d_in[7];
    const float* b_ih1 = (const float*)d_in[8];
    const float* b_hh1 = (const float*)d_in[9];
    float* out = (float*)d_out;

    const size_t H1_BYTES = (size_t)T_LEN * BATCH * 64 * sizeof(float);   // 134 MiB
    const size_t ST_BYTES = (size_t)512 * 64 * sizeof(float);             // 128 KiB
    const size_t SLACK    = (size_t)PF * BATCH * 128 * sizeof(float);     // 1 MiB prefetch overrun

    int C = 0;
    if (ws_size > H1_BYTES + ST_BYTES + SLACK) {
        size_t avail = ws_size - H1_BYTES - ST_BYTES - SLACK;
        for (int nc = 1; nc <= 32; nc <<= 1) {
            size_t xg_bytes = (size_t)2 * (T_LEN / nc) * BATCH * 128 * sizeof(float);
            if (xg_bytes <= avail) { C = T_LEN / nc; break; }
        }
    }

    if (C >= 64) {
        float* h1 = (float*)d_ws;
        float* st = (float*)((char*)d_ws + H1_BYTES);
        float* xg = (float*)((char*)d_ws + H1_BYTES + ST_BYTES);
        dim3 gb(256), rb(64), rg(BATCH);
        for (int t_base = 0; t_base < T_LEN; t_base += C) {
            dim3 gg(C / 16, BATCH);
            hipLaunchKernelGGL((xg_gemm_chunk<0>), gg, gb, 0, stream,
                               OS, IS, (const float*)nullptr, W_ih0, b_ih0, b_hh0, xg, t_base, C);
            hipLaunchKernelGGL((lstm_rec2<0>), rg, rb, 0, stream,
                               xg, W_hh0, h1, st, t_base, C);
        }
        for (int t_base = 0; t_base < T_LEN; t_base += C) {
            dim3 gg(C / 16, BATCH);
            hipLaunchKernelGGL((xg_gemm_chunk<1>), gg, gb, 0, stream,
                               (const float*)nullptr, (const float*)nullptr, h1,
                               W_ih1, b_ih1, b_hh1, xg, t_base, C);
            hipLaunchKernelGGL((lstm_rec2<1>), rg, rb, 0, stream,
                               xg, W_hh1, out, st, t_base, C);
        }
    } else {
        float* h1 = (float*)d_ws;
        dim3 grid(BATCH, 2), block(64);
        hipLaunchKernelGGL((lstm_rec<0>), grid, block, 0, stream,
                           OS, IS, W_ih0, W_hh0, b_ih0, b_hh0, (const float*)nullptr, h1);
        hipLaunchKernelGGL((lstm_rec<1>), grid, block, 0, stream,
                           (const float*)nullptr, (const float*)nullptr,
                           W_ih1, W_hh1, b_ih1, b_hh1, (const float*)h1, out);
    }
}

// Round 5
// 1912.674 us; speedup vs baseline: 1.4199x; 1.4199x over previous
//
#include <hip/hip_runtime.h>

// LSTMencoder: 2-layer biLSTM, B=256, T=2048, H=32 (4H=128 gates), in=32/64.
//
// R5 structure: time-chunked xg precompute + serial recurrence, with the
// NEXT chunk's gemm FUSED into the rec launch (blocks 512+) so it runs on
// the ~94% of SIMDs the 512 rec waves leave idle. Ping-pong xg buffers
// (C=512). gemm body = R2-verified LDS-staged version; rec body = R3-verified
// single-chain version (asm-pinned weights, readlane broadcast, hoisted
// lane-const selects, incremental pointers).
// R4 lesson: dual-chain + LDS h-broadcast regressed (halved waves, LDS
// round-trip on serial path) -> reverted.
// Path B fallback: original harness-verified fused kernel (tiny ws).

#define T_LEN 2048
#define BATCH 256
#define HID   32
#define PF    8
#define REC_BLOCKS 512

__device__ __forceinline__ float frcp(float x) { return __builtin_amdgcn_rcpf(x); }
__device__ __forceinline__ float rdlane(float v, int k) {
    return __int_as_float(__builtin_amdgcn_readlane(__float_as_int(v), k));
}

template<int N>
__device__ __forceinline__ void load_row(float* dst, const float* __restrict__ src) {
#pragma unroll
    for (int i = 0; i < N / 4; ++i) {
        float4 v = reinterpret_cast<const float4*>(src)[i];
        dst[4*i+0] = v.x; dst[4*i+1] = v.y; dst[4*i+2] = v.z; dst[4*i+3] = v.w;
    }
}

// ===================== gemm body (R2-verified LDS-staged) =====================
// flattened block id gb: b = gb & 255, time-tile = gb >> 8.
// LAYER 0: x[te][f] = f<16 ? OS[b][te][f] : IS[b][T-1-te][f-16]  (F=32)
// LAYER 1: x[te][f] = h1[te][b][f]                                (F=64)
template<int LAYER>
__device__ __forceinline__ void gemm_body(
        int gb,
        const float* __restrict__ OS, const float* __restrict__ IS,
        const float* __restrict__ h1,
        const float* __restrict__ Wih, const float* __restrict__ bih,
        const float* __restrict__ bhh, float* __restrict__ xg,
        int t_base, int C)
{
    constexpr int F  = (LAYER == 0) ? 32 : 64;
    constexpr int TT = 16;                      // timesteps per block (per dir)
    __shared__ float xs[2][TT][F];
    const int tid = threadIdx.x;
    const int d   = tid >> 7;                   // 0..1
    const int g   = tid & 127;                  // 0..127
    const int b   = gb & (BATCH - 1);
    const int lt0 = (gb >> 8) * TT;             // local chunk offset

    // stage x tiles for BOTH dirs into LDS (coalesced in f)
    constexpr int TOT = 2 * TT * F;             // 1024 (L0) / 2048 (L1)
#pragma unroll
    for (int rep = 0; rep < TOT / 256; ++rep) {
        int flat = rep * 256 + tid;
        int d2  = flat / (TT * F);
        int rem = flat % (TT * F);
        int tt  = rem / F, f = rem % F;
        int tl  = t_base + lt0 + tt;
        int te  = d2 ? (T_LEN - 1 - tl) : tl;
        float v;
        if (LAYER == 0) {
            v = (f < 16) ? OS[((size_t)b * T_LEN + te) * 16 + f]
                         : IS[((size_t)b * T_LEN + (T_LEN - 1 - te)) * 16 + (f - 16)];
        } else {
            v = h1[((size_t)te * BATCH + b) * 64 + f];
        }
        xs[d2][tt][f] = v;
    }

    float w[F];
    load_row<F>(w, Wih + ((size_t)d * 128 + g) * F);
    const float bias = bih[d * 128 + g] + bhh[d * 128 + g];
    __syncthreads();

#pragma unroll
    for (int tt = 0; tt < TT; ++tt) {
        float a0 = bias, a1 = 0.f, a2 = 0.f, a3 = 0.f;
#pragma unroll
        for (int j = 0; j < F / 4; ++j) {
            float4 x = reinterpret_cast<const float4*>(xs[d][tt])[j];
            a0 = fmaf(x.x, w[4*j+0], a0);
            a1 = fmaf(x.y, w[4*j+1], a1);
            a2 = fmaf(x.z, w[4*j+2], a2);
            a3 = fmaf(x.w, w[4*j+3], a3);
        }
        xg[(((size_t)d * C + (lt0 + tt)) * BATCH + b) * 128 + g] = (a0 + a1) + (a2 + a3);
    }
}

// ===================== rec body (R3-verified single-chain) =====================
// rb in [0,512): b = rb & 255, d = rb >> 8. Lane l owns gates (l, 64+l).
template<int LAYER>
__device__ __forceinline__ void rec_body(
        int rb, const float* __restrict__ xg, const float* __restrict__ Whh,
        float* __restrict__ outp, float* __restrict__ state,
        int t_base, int C)
{
    const int l   = threadIdx.x;     // 0..63
    const int b   = rb & (BATCH - 1);
    const int d   = rb >> 8;         // 0 fwd, 1 bwd
    const bool lo = (l < HID);
    const int chain = d * BATCH + b;
    const int xl  = (l + 32) & 63;   // swap partner

    // lane-constant nonlinearity params (hoisted: no per-step selects)
    const float mB = lo ? -2.f : -1.f;   // tanh arg scale (g) vs sigmoid (o)
    const float kM = lo ?  2.f :  1.f;
    const float kA = lo ? -1.f :  0.f;

    float wa[HID], wb[HID];
    load_row<HID>(wa, Whh + ((size_t)d * 128 + l) * HID);
    load_row<HID>(wb, Whh + ((size_t)d * 128 + 64 + l) * HID);

    // restore state (zeros at t_base==0)
    float c = 0.f, hj = 0.f;
    if (t_base > 0 && lo) {
        c  = state[(size_t)chain * 64 + l];
        hj = state[(size_t)chain * 64 + 32 + l];
    }
    float h[HID];                    // wave-uniform via readlane (SGPRs)
#pragma unroll
    for (int k = 0; k < HID; ++k) h[k] = rdlane(hj, k);

    const size_t STRIDE = (size_t)BATCH * 128;
    const float* xp = xg + (size_t)d * C * STRIDE + (size_t)b * 128;
    const float* pf = xp + (size_t)PF * STRIDE;   // prefetch cursor

    float ra[PF], rb_[PF];
#pragma unroll
    for (int u = 0; u < PF; ++u) {
        ra[u]  = xp[(size_t)u * STRIDE + l];
        rb_[u] = xp[(size_t)u * STRIDE + 64 + l];
    }

    // incremental output pointer
    const int te0 = d ? (T_LEN - 1 - t_base) : t_base;
    float* op;
    ptrdiff_t ostep;
    if constexpr (LAYER == 0) {
        op = outp + ((size_t)te0 * BATCH + b) * 64 + d * HID + l;
        ostep = d ? -(ptrdiff_t)(BATCH * 64) : (ptrdiff_t)(BATCH * 64);
    } else {
        op = outp + ((size_t)b * T_LEN + te0) * 64 + d * HID + l;
        ostep = d ? (ptrdiff_t)-64 : (ptrdiff_t)64;
    }

#pragma unroll 1
    for (int tb = 0; tb < C; tb += PF) {
        // pin W in VGPRs: asm redefines values -> compiler cannot remat loads
#pragma unroll
        for (int k = 0; k < HID; k += 4)
            asm volatile("" : "+v"(wa[k]), "+v"(wa[k+1]), "+v"(wa[k+2]), "+v"(wa[k+3]));
#pragma unroll
        for (int k = 0; k < HID; k += 4)
            asm volatile("" : "+v"(wb[k]), "+v"(wb[k+1]), "+v"(wb[k+2]), "+v"(wb[k+3]));

#pragma unroll
        for (int u = 0; u < PF; ++u) {
            const float xa = ra[u], xb = rb_[u];
            ra[u]  = pf[l];              // prefetch step lt+PF (overrun is dead)
            rb_[u] = pf[64 + l];
            pf += STRIDE;

            // recurrent dot: 8 independent FMA chains of length 8
            float a0 = xa, a1 = 0.f, a2 = 0.f, a3 = 0.f;
            float b0 = xb, b1 = 0.f, b2 = 0.f, b3 = 0.f;
#pragma unroll
            for (int k = 0; k < 8; ++k) {
                a0 = fmaf(h[k],      wa[k],      a0);
                a1 = fmaf(h[k + 8],  wa[k + 8],  a1);
                a2 = fmaf(h[k + 16], wa[k + 16], a2);
                a3 = fmaf(h[k + 24], wa[k + 24], a3);
                b0 = fmaf(h[k],      wb[k],      b0);
                b1 = fmaf(h[k + 8],  wb[k + 8],  b1);
                b2 = fmaf(h[k + 16], wb[k + 16], b2);
                b3 = fmaf(h[k + 24], wb[k + 24], b3);
            }
            const float accA = (a0 + a1) + (a2 + a3);
            const float accB = (b0 + b1) + (b2 + b3);

            // sA = sigmoid(accA); sB = tanh(accB) [lo] or sigmoid(accB) [hi]
            const float sA = frcp(1.f + __expf(-accA));
            const float rB = frcp(1.f + __expf(mB * accB));
            const float sB = fmaf(kM, rB, kA);
            const float sf = __shfl(sA, xl);    // sig(f) to lanes<32
            const float so = __shfl(sB, xl);    // sig(o) to lanes<32
            c = fmaf(sf, c, sA * sB);
            const float tc = fmaf(2.f, frcp(1.f + __expf(-2.f * c)), -1.f);
            hj = so * tc;
            if (lo) *op = hj;
            op += ostep;
#pragma unroll
            for (int k = 0; k < HID; ++k) h[k] = rdlane(hj, k);
        }
    }

    if (lo) {
        state[(size_t)chain * 64 + l]      = c;
        state[(size_t)chain * 64 + 32 + l] = hj;
    }
}

// ===================== kernels =====================
template<int LAYER>
__global__ __launch_bounds__(256) void xg_gemm_k(
        const float* __restrict__ OS, const float* __restrict__ IS,
        const float* __restrict__ h1,
        const float* __restrict__ Wih, const float* __restrict__ bih,
        const float* __restrict__ bhh, float* __restrict__ xg,
        int t_base, int C)
{
    gemm_body<LAYER>(blockIdx.x, OS, IS, h1, Wih, bih, bhh, xg, t_base, C);
}

template<int LAYER>
__global__ __launch_bounds__(64, 1) void lstm_rec_k(
        const float* __restrict__ xg, const float* __restrict__ Whh,
        float* __restrict__ outp, float* __restrict__ state,
        int t_base, int C)
{
    rec_body<LAYER>(blockIdx.x, xg, Whh, outp, state, t_base, C);
}

// rec for chunk i (xg_rec) + gemm for chunk i+1 (xg_next) in ONE launch.
// Blocks [0,512): rec (threads 64..255 exit). Blocks 512+: gemm.
template<int LAYER>
__global__ __launch_bounds__(256, 2) void fused_rec_gemm(
        const float* __restrict__ OS, const float* __restrict__ IS,
        const float* __restrict__ h1,
        const float* __restrict__ Wih, const float* __restrict__ bih,
        const float* __restrict__ bhh,
        const float* __restrict__ xg_rec, float* __restrict__ xg_next,
        const float* __restrict__ Whh,
        float* __restrict__ outp, float* __restrict__ state,
        int t_base_rec, int t_base_gemm, int C)
{
    if (blockIdx.x < REC_BLOCKS) {
        if (threadIdx.x >= 64) return;
        __builtin_amdgcn_s_setprio(1);   // rec is the critical path
        rec_body<LAYER>(blockIdx.x, xg_rec, Whh, outp, state, t_base_rec, C);
    } else {
        gemm_body<LAYER>(blockIdx.x - REC_BLOCKS, OS, IS, h1,
                         Wih, bih, bhh, xg_next, t_base_gemm, C);
    }
}

// ===================== Path B: original verified fused kernel =====================
template<int LAYER>
__global__ __launch_bounds__(64, 1) void lstm_rec(
        const float* __restrict__ OS, const float* __restrict__ IS,
        const float* __restrict__ Wih, const float* __restrict__ Whh,
        const float* __restrict__ bih, const float* __restrict__ bhh,
        const float* __restrict__ h1in, float* __restrict__ outp)
{
    constexpr int F = (LAYER == 0) ? 32 : 64;
    const int l   = threadIdx.x;
    const int b   = blockIdx.x;
    const int dir = blockIdx.y;
    const int gA  = l;
    const int gB  = 64 + l;

    float wih_a[F], wih_b[F], whh_a[HID], whh_b[HID];
    load_row<F>(wih_a, Wih + ((size_t)dir * 128 + gA) * F);
    load_row<F>(wih_b, Wih + ((size_t)dir * 128 + gB) * F);
    load_row<HID>(whh_a, Whh + ((size_t)dir * 128 + gA) * HID);
    load_row<HID>(whh_b, Whh + ((size_t)dir * 128 + gB) * HID);
    const float biasA = bih[dir * 128 + gA] + bhh[dir * 128 + gA];
    const float biasB = bih[dir * 128 + gB] + bhh[dir * 128 + gB];

    float h[HID];
#pragma unroll
    for (int k = 0; k < HID; ++k) h[k] = 0.f;
    float c = 0.f;
    const bool lo = (l < HID);

    float4 X0[F / 4], X1[F / 4];

    auto load_x = [&](float4* X, int tl) {
        const int te = dir ? (T_LEN - 1 - tl) : tl;
        if constexpr (LAYER == 0) {
            const float4* p0 = reinterpret_cast<const float4*>(OS + ((size_t)b * T_LEN + te) * 16);
            const float4* p1 = reinterpret_cast<const float4*>(IS + ((size_t)b * T_LEN + (T_LEN - 1 - te)) * 16);
#pragma unroll
            for (int i = 0; i < 4; ++i) X[i] = p0[i];
#pragma unroll
            for (int i = 0; i < 4; ++i) X[4 + i] = p1[i];
        } else {
            const float4* p = reinterpret_cast<const float4*>(h1in + ((size_t)te * BATCH + b) * 64);
#pragma unroll
            for (int i = 0; i < F / 4; ++i) X[i] = p[i];
        }
    };

    auto step = [&](int tl, const float4* X) {
        const int te = dir ? (T_LEN - 1 - tl) : tl;
        float accA = biasA, accB = biasB;
#pragma unroll
        for (int i = 0; i < F / 4; ++i) {
            accA = fmaf(X[i].x, wih_a[4*i+0], accA);
            accA = fmaf(X[i].y, wih_a[4*i+1], accA);
            accA = fmaf(X[i].z, wih_a[4*i+2], accA);
            accA = fmaf(X[i].w, wih_a[4*i+3], accA);
            accB = fmaf(X[i].x, wih_b[4*i+0], accB);
            accB = fmaf(X[i].y, wih_b[4*i+1], accB);
            accB = fmaf(X[i].z, wih_b[4*i+2], accB);
            accB = fmaf(X[i].w, wih_b[4*i+3], accB);
        }
#pragma unroll
        for (int k = 0; k < HID; ++k) {
            accA = fmaf(h[k], whh_a[k], accA);
            accB = fmaf(h[k], whh_b[k], accB);
        }
        float sA = frcp(1.f + __expf(-accA));
        float argB = lo ? (-2.f * accB) : (-accB);
        float rB = frcp(1.f + __expf(argB));
        float sB = lo ? fmaf(2.f, rB, -1.f) : rB;
        float sf = __shfl(sA, (l + 32) & 63);
        float so = __shfl(sB, (l + 32) & 63);
        c = fmaf(sf, c, sA * sB);
        float tc = fmaf(2.f, frcp(1.f + __expf(-2.f * c)), -1.f);
        float hj = so * tc;
        if (lo) {
            if constexpr (LAYER == 0)
                outp[((size_t)te * BATCH + b) * 64 + dir * HID + l] = hj;
            else
                outp[((size_t)b * T_LEN + te) * 64 + dir * HID + l] = hj;
        }
#pragma unroll
        for (int k = 0; k < HID; ++k) h[k] = rdlane(hj, k);
    };

    load_x(X0, 0);
#pragma unroll 1
    for (int tt = 0; tt < T_LEN; tt += 2) {
        load_x(X1, tt + 1);
        step(tt, X0);
        int nx = tt + 2; if (nx > T_LEN - 1) nx = T_LEN - 1;
        load_x(X0, nx);
        step(tt + 1, X1);
    }
}

extern "C" void kernel_launch(void* const* d_in, const int* in_sizes, int n_in,
                              void* d_out, int out_size, void* d_ws, size_t ws_size,
                              hipStream_t stream) {
    const float* OS    = (const float*)d_in[0];
    const float* IS    = (const float*)d_in[1];
    const float* W_ih0 = (const float*)d_in[2];
    const float* W_hh0 = (const float*)d_in[3];
    const float* b_ih0 = (const float*)d_in[4];
    const float* b_hh0 = (const float*)d_in[5];
    const float* W_ih1 = (const float*)d_in[6];
    const float* W_hh1 = (const float*)d_in[7];
    const float* b_ih1 = (const float*)d_in[8];
    const float* b_hh1 = (const float*)d_in[9];
    float* out = (float*)d_out;

    const size_t H1_BYTES = (size_t)T_LEN * BATCH * 64 * sizeof(float);   // 134 MiB
    const size_t ST_BYTES = (size_t)512 * 64 * sizeof(float);             // 128 KiB
    const size_t SLACK    = (size_t)PF * BATCH * 128 * sizeof(float);     // 1 MiB

    // pick largest fused chunk C with ping-pong xg buffers
    int C = 0;
    for (int c = 512; c >= 64; c >>= 1) {
        size_t xgc = (size_t)2 * c * BATCH * 128 * sizeof(float);
        if (H1_BYTES + ST_BYTES + 2 * xgc + SLACK <= ws_size) { C = c; break; }
    }

    if (C >= 64) {
        const int NC = T_LEN / C;
        const size_t xgc = (size_t)2 * C * BATCH * 128 * sizeof(float);
        float* h1  = (float*)d_ws;
        float* st  = (float*)((char*)d_ws + H1_BYTES);
        float* xgA = (float*)((char*)d_ws + H1_BYTES + ST_BYTES);
        float* xgB = (float*)((char*)d_ws + H1_BYTES + ST_BYTES + xgc);
        float* xgbuf[2] = { xgA, xgB };

        const int GEMM_BLOCKS = (C / 16) * BATCH;
        dim3 gb(256), rb(64);

        // ---------------- layer 0 ----------------
        hipLaunchKernelGGL((xg_gemm_k<0>), dim3(GEMM_BLOCKS), gb, 0, stream,
                           OS, IS, (const float*)nullptr, W_ih0, b_ih0, b_hh0,
                           xgbuf[0], 0, C);
        for (int i = 0; i < NC; ++i) {
            const float* xr = xgbuf[i & 1];
            if (i + 1 < NC) {
                hipLaunchKernelGGL((fused_rec_gemm<0>),
                                   dim3(REC_BLOCKS + GEMM_BLOCKS), gb, 0, stream,
                                   OS, IS, (const float*)nullptr,
                                   W_ih0, b_ih0, b_hh0,
                                   xr, xgbuf[(i + 1) & 1], W_hh0,
                                   h1, st, i * C, (i + 1) * C, C);
            } else {
                hipLaunchKernelGGL((lstm_rec_k<0>), dim3(REC_BLOCKS), rb, 0, stream,
                                   xr, W_hh0, h1, st, i * C, C);
            }
        }
        // ---------------- layer 1 ----------------
        hipLaunchKernelGGL((xg_gemm_k<1>), dim3(GEMM_BLOCKS), gb, 0, stream,
                           (const float*)nullptr, (const float*)nullptr, h1,
                           W_ih1, b_ih1, b_hh1, xgbuf[0], 0, C);
        for (int i = 0; i < NC; ++i) {
            const float* xr = xgbuf[i & 1];
            if (i + 1 < NC) {
                hipLaunchKernelGGL((fused_rec_gemm<1>),
                                   dim3(REC_BLOCKS + GEMM_BLOCKS), gb, 0, stream,
                                   (const float*)nullptr, (const float*)nullptr, h1,
                                   W_ih1, b_ih1, b_hh1,
                                   xr, xgbuf[(i + 1) & 1], W_hh1,
                                   out, st, i * C, (i + 1) * C, C);
            } else {
                hipLaunchKernelGGL((lstm_rec_k<1>), dim3(REC_BLOCKS), rb, 0, stream,
                                   xr, W_hh1, out, st, i * C, C);
            }
        }
    } else {
        // -------- Path B: original verified fallback --------
        float* h1 = (float*)d_ws;
        dim3 grid(BATCH, 2), block(64);
        hipLaunchKernelGGL((lstm_rec<0>), grid, block, 0, stream,
                           OS, IS, W_ih0, W_hh0, b_ih0, b_hh0, (const float*)nullptr, h1);
        hipLaunchKernelGGL((lstm_rec<1>), grid, block, 0, stream,
                           (const float*)nullptr, (const float*)nullptr,
                           W_ih1, W_hh1, b_ih1, b_hh1, (const float*)h1, out);
    }
}